// Round 1
// baseline (1685.018 us; speedup 1.0000x reference)
//
#include <hip/hip_runtime.h>

// TimeDecayMultiheadAttention on MI355X (gfx950)
// T=2048, B=2, E=1024, H=16, D=64. All math in bf16 MFMA / fp32 accum.
//
// Pipeline:
//  1) cvt: x (4096x1024 f32) -> bf16; Wq/Wk/Wv/Wo (1024x1024 f32) -> bf16
//  2) gemm_qkv: C = xb @ W^T + b, scatter to (B,H,T,D) bf16, z in {Q,K,V}
//  3) attn: wave-per-row softmax attention (causal), out -> Ob (4096x1024 bf16)
//  4) gemm_out: out = (Ob @ Wo^T + bo) * time_decay -> f32 d_out

typedef unsigned short u16;
typedef __attribute__((ext_vector_type(8))) short bf16x8_t;  // 8 bf16 (4 VGPRs)
typedef __attribute__((ext_vector_type(4))) float fx4_t;     // 4 fp32 acc

#define T_SEQ 2048
#define BATCH 2
#define EMB   1024
#define NH    16
#define HD    64
#define MROWS (T_SEQ * BATCH) // 4096

__device__ __forceinline__ float bf2f(u16 u) {
  union { unsigned int i; float f; } v;
  v.i = ((unsigned int)u) << 16;
  return v.f;
}
__device__ __forceinline__ u16 f2bf(float f) {
  union { float f; unsigned int i; } v;
  v.f = f;
  unsigned int x = v.i;
  unsigned int r = (x + 0x7fffu + ((x >> 16) & 1u)) >> 16; // round-nearest-even
  return (u16)r;
}

// ---------------- conversion: f32 -> bf16, 4 elems/thread ----------------
__global__ void cvt_f32_bf16(const float* __restrict__ src, u16* __restrict__ dst, int n4) {
  int i = blockIdx.x * blockDim.x + threadIdx.x;
  if (i < n4) {
    float4 v = ((const float4*)src)[i];
    ushort4 o;
    o.x = f2bf(v.x); o.y = f2bf(v.y); o.z = f2bf(v.z); o.w = f2bf(v.w);
    ((ushort4*)dst)[i] = o;
  }
}

// ---------------- QKV projection GEMM ----------------
// C[m][n] = sum_k xb[m][k] * W[n][k] + bias[n]  (m in 4096, n in 1024, k in 1024)
// scatter: t=m>>1, b=m&1, h=n>>6, d=n&63 -> dst[((b*16+h)*2048+t)*64+d]
__global__ __launch_bounds__(256, 2) void gemm_qkv(
    const u16* __restrict__ xb,
    const u16* __restrict__ wq, const u16* __restrict__ wk, const u16* __restrict__ wv,
    const float* __restrict__ bq, const float* __restrict__ bk, const float* __restrict__ bv,
    u16* __restrict__ Qh, u16* __restrict__ Kh, u16* __restrict__ Vh) {
  __shared__ short As[128 * 72]; // 72-elem row stride: 144B = 36 banks -> 2-way max (free)
  __shared__ short Bs[128 * 72];

  const int z = blockIdx.z;
  const u16* W = (z == 0) ? wq : (z == 1) ? wk : wv;
  const float* bias = (z == 0) ? bq : (z == 1) ? bk : bv;
  u16* dst = (z == 0) ? Qh : (z == 1) ? Kh : Vh;

  const int tid = threadIdx.x;
  const int bm = blockIdx.x, bn = blockIdx.y;
  const int lane = tid & 63, wv_id = tid >> 6;
  const int wm = wv_id >> 1, wn = wv_id & 1;
  const int lr = lane & 15, quad = lane >> 4;

  fx4_t acc[4][4];
#pragma unroll
  for (int i = 0; i < 4; i++)
#pragma unroll
    for (int j = 0; j < 4; j++) acc[i][j] = (fx4_t){0.f, 0.f, 0.f, 0.f};

  for (int k0 = 0; k0 < EMB; k0 += 64) {
#pragma unroll
    for (int it = 0; it < 4; ++it) {
      int g = tid + it * 256;        // 1024 granules of 8 bf16
      int r = g >> 3, c = g & 7;
      const int4* sa = (const int4*)(xb + (size_t)(bm * 128 + r) * EMB + k0 + c * 8);
      *(int4*)&As[r * 72 + c * 8] = *sa;
      const int4* sb = (const int4*)(W + (size_t)(bn * 128 + r) * EMB + k0 + c * 8);
      *(int4*)&Bs[r * 72 + c * 8] = *sb;
    }
    __syncthreads();
#pragma unroll
    for (int ks = 0; ks < 2; ++ks) {
      bf16x8_t a[4], b[4];
      const int goff = (ks * 4 + quad) * 8;
#pragma unroll
      for (int i = 0; i < 4; i++) a[i] = *(const bf16x8_t*)&As[(wm * 64 + i * 16 + lr) * 72 + goff];
#pragma unroll
      for (int j = 0; j < 4; j++) b[j] = *(const bf16x8_t*)&Bs[(wn * 64 + j * 16 + lr) * 72 + goff];
#pragma unroll
      for (int i = 0; i < 4; i++)
#pragma unroll
        for (int j = 0; j < 4; j++)
          acc[i][j] = __builtin_amdgcn_mfma_f32_16x16x32_bf16(a[i], b[j], acc[i][j], 0, 0, 0);
    }
    __syncthreads();
  }

#pragma unroll
  for (int i = 0; i < 4; i++) {
#pragma unroll
    for (int j = 0; j < 4; j++) {
      const int n = bn * 128 + wn * 64 + j * 16 + lr;
      const float bsv = bias[n];
      const int h = n >> 6, d = n & 63;
#pragma unroll
      for (int r = 0; r < 4; r++) {
        const int m = bm * 128 + wm * 64 + i * 16 + quad * 4 + r;
        const int t = m >> 1, bb = m & 1;
        float v = acc[i][j][r] + bsv;
        dst[((size_t)(bb * NH + h) * T_SEQ + t) * HD + d] = f2bf(v);
      }
    }
  }
}

// ---------------- output projection GEMM ----------------
// out[m][n] = (sum_k Ob[m][k] * Wo[n][k] + bo[n]) * td[m], f32 out
__global__ __launch_bounds__(256, 2) void gemm_out(
    const u16* __restrict__ Ob, const u16* __restrict__ wo,
    const float* __restrict__ bo, const float* __restrict__ td,
    float* __restrict__ out) {
  __shared__ short As[128 * 72];
  __shared__ short Bs[128 * 72];

  const int tid = threadIdx.x;
  const int bm = blockIdx.x, bn = blockIdx.y;
  const int lane = tid & 63, wv_id = tid >> 6;
  const int wm = wv_id >> 1, wn = wv_id & 1;
  const int lr = lane & 15, quad = lane >> 4;

  fx4_t acc[4][4];
#pragma unroll
  for (int i = 0; i < 4; i++)
#pragma unroll
    for (int j = 0; j < 4; j++) acc[i][j] = (fx4_t){0.f, 0.f, 0.f, 0.f};

  for (int k0 = 0; k0 < EMB; k0 += 64) {
#pragma unroll
    for (int it = 0; it < 4; ++it) {
      int g = tid + it * 256;
      int r = g >> 3, c = g & 7;
      const int4* sa = (const int4*)(Ob + (size_t)(bm * 128 + r) * EMB + k0 + c * 8);
      *(int4*)&As[r * 72 + c * 8] = *sa;
      const int4* sb = (const int4*)(wo + (size_t)(bn * 128 + r) * EMB + k0 + c * 8);
      *(int4*)&Bs[r * 72 + c * 8] = *sb;
    }
    __syncthreads();
#pragma unroll
    for (int ks = 0; ks < 2; ++ks) {
      bf16x8_t a[4], b[4];
      const int goff = (ks * 4 + quad) * 8;
#pragma unroll
      for (int i = 0; i < 4; i++) a[i] = *(const bf16x8_t*)&As[(wm * 64 + i * 16 + lr) * 72 + goff];
#pragma unroll
      for (int j = 0; j < 4; j++) b[j] = *(const bf16x8_t*)&Bs[(wn * 64 + j * 16 + lr) * 72 + goff];
#pragma unroll
      for (int i = 0; i < 4; i++)
#pragma unroll
        for (int j = 0; j < 4; j++)
          acc[i][j] = __builtin_amdgcn_mfma_f32_16x16x32_bf16(a[i], b[j], acc[i][j], 0, 0, 0);
    }
    __syncthreads();
  }

#pragma unroll
  for (int i = 0; i < 4; i++) {
#pragma unroll
    for (int j = 0; j < 4; j++) {
      const int n = bn * 128 + wn * 64 + j * 16 + lr;
      const float bsv = bo[n];
#pragma unroll
      for (int r = 0; r < 4; r++) {
        const int m = bm * 128 + wm * 64 + i * 16 + quad * 4 + r;
        float v = (acc[i][j][r] + bsv) * td[m];
        out[(size_t)m * EMB + n] = v;
      }
    }
  }
}

// ---------------- attention: wave-per-(head,row), causal softmax ----------------
__global__ __launch_bounds__(256, 2) void attn(
    const u16* __restrict__ Qh, const u16* __restrict__ Kh, const u16* __restrict__ Vh,
    u16* __restrict__ Ob) {
  __shared__ float q_s[4][64];
  __shared__ float p_s[4][2048];

  const int w = threadIdx.x >> 6, lane = threadIdx.x & 63;
  const int row = blockIdx.x * 4 + w;   // 0..65535
  const int bh = row >> 11, t = row & 2047;
  const u16* Kb = Kh + (size_t)bh * T_SEQ * HD;
  const u16* Vb = Vh + (size_t)bh * T_SEQ * HD;
  const u16* Qr = Qh + ((size_t)bh * T_SEQ + t) * HD;

  q_s[w][lane] = bf2f(Qr[lane]); // wave-synchronous LDS (single wave writes+reads)

  const int nk = t + 1;
  float lmax = -1e30f;
  for (int k = lane; k < nk; k += 64) {
    const int4* kr = (const int4*)(Kb + (size_t)k * HD);
    float dacc = 0.f;
#pragma unroll
    for (int c = 0; c < 8; c++) {
      int4 pk = kr[c];
      const u16* us = (const u16*)&pk;
#pragma unroll
      for (int e = 0; e < 8; e++) dacc += bf2f(us[e]) * q_s[w][c * 8 + e];
    }
    float s = dacc * 0.125f; // 1/sqrt(64)
    p_s[w][k] = s;
    lmax = fmaxf(lmax, s);
  }
#pragma unroll
  for (int off = 32; off; off >>= 1) lmax = fmaxf(lmax, __shfl_xor(lmax, off));

  float lsum = 0.f;
  for (int k = lane; k < nk; k += 64) {
    float e = __expf(p_s[w][k] - lmax);
    p_s[w][k] = e;
    lsum += e;
  }
#pragma unroll
  for (int off = 32; off; off >>= 1) lsum += __shfl_xor(lsum, off);
  const float inv = 1.0f / lsum;

  // PV: lane owns output dim d = lane
  const u16* vp = Vb + lane;
  float o0 = 0.f, o1 = 0.f, o2 = 0.f, o3 = 0.f;
  int k = 0;
  for (; k + 4 <= nk; k += 4) {
    float4 p4 = *(const float4*)&p_s[w][k];
    o0 += p4.x * bf2f(vp[(size_t)(k + 0) * HD]);
    o1 += p4.y * bf2f(vp[(size_t)(k + 1) * HD]);
    o2 += p4.z * bf2f(vp[(size_t)(k + 2) * HD]);
    o3 += p4.w * bf2f(vp[(size_t)(k + 3) * HD]);
  }
  for (; k < nk; ++k) o0 += p_s[w][k] * bf2f(vp[(size_t)k * HD]);

  const float o = (o0 + o1 + o2 + o3) * inv;
  const int b = bh >> 4, h = bh & 15;
  Ob[(size_t)(t * BATCH + b) * EMB + h * HD + lane] = f2bf(o);
}

// ---------------- launch ----------------
extern "C" void kernel_launch(void* const* d_in, const int* in_sizes, int n_in,
                              void* d_out, int out_size, void* d_ws, size_t ws_size,
                              hipStream_t stream) {
  const float* x  = (const float*)d_in[0];
  const float* td = (const float*)d_in[1];
  // d_in[2] attn_mask: fixed causal tril, handled analytically
  const float* Wq = (const float*)d_in[3];
  const float* bq = (const float*)d_in[4];
  const float* Wk = (const float*)d_in[5];
  const float* bk = (const float*)d_in[6];
  const float* Wv = (const float*)d_in[7];
  const float* bv = (const float*)d_in[8];
  const float* Wo = (const float*)d_in[9];
  const float* bo = (const float*)d_in[10];
  float* out = (float*)d_out;

  char* ws = (char*)d_ws;
  u16* xb  = (u16*)(ws + 0);                     // 8 MB (reused as Ob after gemm_qkv)
  u16* wqb = (u16*)(ws + ((size_t)8  << 20));    // 2 MB
  u16* wkb = (u16*)(ws + ((size_t)10 << 20));    // 2 MB
  u16* wvb = (u16*)(ws + ((size_t)12 << 20));    // 2 MB
  u16* wob = (u16*)(ws + ((size_t)14 << 20));    // 2 MB
  u16* Qh  = (u16*)(ws + ((size_t)16 << 20));    // 8 MB
  u16* Kh  = (u16*)(ws + ((size_t)24 << 20));    // 8 MB
  u16* Vh  = (u16*)(ws + ((size_t)32 << 20));    // 8 MB  (total 40 MB)
  u16* Ob  = xb;                                  // alias: xb dead after gemm_qkv

  cvt_f32_bf16<<<(MROWS * EMB / 4 + 255) / 256, 256, 0, stream>>>(x, xb, MROWS * EMB / 4);
  cvt_f32_bf16<<<(EMB * EMB / 4 + 255) / 256, 256, 0, stream>>>(Wq, wqb, EMB * EMB / 4);
  cvt_f32_bf16<<<(EMB * EMB / 4 + 255) / 256, 256, 0, stream>>>(Wk, wkb, EMB * EMB / 4);
  cvt_f32_bf16<<<(EMB * EMB / 4 + 255) / 256, 256, 0, stream>>>(Wv, wvb, EMB * EMB / 4);
  cvt_f32_bf16<<<(EMB * EMB / 4 + 255) / 256, 256, 0, stream>>>(Wo, wob, EMB * EMB / 4);

  gemm_qkv<<<dim3(MROWS / 128, EMB / 128, 3), 256, 0, stream>>>(
      xb, wqb, wkb, wvb, bq, bk, bv, Qh, Kh, Vh);

  attn<<<(BATCH * NH * T_SEQ) / 4, 256, 0, stream>>>(Qh, Kh, Vh, Ob);

  gemm_out<<<dim3(MROWS / 128, EMB / 128), 256, 0, stream>>>(Ob, wob, bo, td, out);
}

// Round 2
// 285.352 us; speedup vs baseline: 5.9051x; 5.9051x over previous
//
#include <hip/hip_runtime.h>

// TimeDecayMultiheadAttention on MI355X (gfx950)
// T=2048, B=2, E=1024, H=16, D=64. All math in bf16 MFMA / fp32 accum.
//
// Pipeline:
//  1) cvt: x (4096x1024 f32) -> bf16; Wq/Wk/Wv/Wo (1024x1024 f32) -> bf16
//  2) gemm_qkv: C = xb @ W^T + b, scatter to (B,H,T,D) bf16, z in {Q,K,V}
//  3) attn_mfma: flash-style causal attention, MFMA QK^T + PV -> Ob bf16
//  4) gemm_out: out = (Ob @ Wo^T + bo) * time_decay -> f32 d_out

typedef unsigned short u16;
typedef __attribute__((ext_vector_type(8))) short bf16x8_t;  // 8 bf16 (4 VGPRs)
typedef __attribute__((ext_vector_type(4))) float fx4_t;     // 4 fp32 acc

#define T_SEQ 2048
#define BATCH 2
#define EMB   1024
#define NH    16
#define HD    64
#define MROWS (T_SEQ * BATCH) // 4096

__device__ __forceinline__ float bf2f(u16 u) {
  union { unsigned int i; float f; } v;
  v.i = ((unsigned int)u) << 16;
  return v.f;
}
__device__ __forceinline__ u16 f2bf(float f) {
  union { float f; unsigned int i; } v;
  v.f = f;
  unsigned int x = v.i;
  unsigned int r = (x + 0x7fffu + ((x >> 16) & 1u)) >> 16; // round-nearest-even
  return (u16)r;
}

// ---------------- conversion: f32 -> bf16, 4 elems/thread ----------------
__global__ void cvt_f32_bf16(const float* __restrict__ src, u16* __restrict__ dst, int n4) {
  int i = blockIdx.x * blockDim.x + threadIdx.x;
  if (i < n4) {
    float4 v = ((const float4*)src)[i];
    ushort4 o;
    o.x = f2bf(v.x); o.y = f2bf(v.y); o.z = f2bf(v.z); o.w = f2bf(v.w);
    ((ushort4*)dst)[i] = o;
  }
}

// ---------------- QKV projection GEMM ----------------
// C[m][n] = sum_k xb[m][k] * W[n][k] + bias[n]  (m in 4096, n in 1024, k in 1024)
// scatter: t=m>>1, b=m&1, h=n>>6, d=n&63 -> dst[((b*16+h)*2048+t)*64+d]
__global__ __launch_bounds__(256, 2) void gemm_qkv(
    const u16* __restrict__ xb,
    const u16* __restrict__ wq, const u16* __restrict__ wk, const u16* __restrict__ wv,
    const float* __restrict__ bq, const float* __restrict__ bk, const float* __restrict__ bv,
    u16* __restrict__ Qh, u16* __restrict__ Kh, u16* __restrict__ Vh) {
  __shared__ short As[128 * 72]; // 72-elem row stride: 144B = 36 banks -> 2-way max (free)
  __shared__ short Bs[128 * 72];

  const int z = blockIdx.z;
  const u16* W = (z == 0) ? wq : (z == 1) ? wk : wv;
  const float* bias = (z == 0) ? bq : (z == 1) ? bk : bv;
  u16* dst = (z == 0) ? Qh : (z == 1) ? Kh : Vh;

  const int tid = threadIdx.x;
  const int bm = blockIdx.x, bn = blockIdx.y;
  const int lane = tid & 63, wv_id = tid >> 6;
  const int wm = wv_id >> 1, wn = wv_id & 1;
  const int lr = lane & 15, quad = lane >> 4;

  fx4_t acc[4][4];
#pragma unroll
  for (int i = 0; i < 4; i++)
#pragma unroll
    for (int j = 0; j < 4; j++) acc[i][j] = (fx4_t){0.f, 0.f, 0.f, 0.f};

  for (int k0 = 0; k0 < EMB; k0 += 64) {
#pragma unroll
    for (int it = 0; it < 4; ++it) {
      int g = tid + it * 256;        // 1024 granules of 8 bf16
      int r = g >> 3, c = g & 7;
      const int4* sa = (const int4*)(xb + (size_t)(bm * 128 + r) * EMB + k0 + c * 8);
      *(int4*)&As[r * 72 + c * 8] = *sa;
      const int4* sb = (const int4*)(W + (size_t)(bn * 128 + r) * EMB + k0 + c * 8);
      *(int4*)&Bs[r * 72 + c * 8] = *sb;
    }
    __syncthreads();
#pragma unroll
    for (int ks = 0; ks < 2; ++ks) {
      bf16x8_t a[4], b[4];
      const int goff = (ks * 4 + quad) * 8;
#pragma unroll
      for (int i = 0; i < 4; i++) a[i] = *(const bf16x8_t*)&As[(wm * 64 + i * 16 + lr) * 72 + goff];
#pragma unroll
      for (int j = 0; j < 4; j++) b[j] = *(const bf16x8_t*)&Bs[(wn * 64 + j * 16 + lr) * 72 + goff];
#pragma unroll
      for (int i = 0; i < 4; i++)
#pragma unroll
        for (int j = 0; j < 4; j++)
          acc[i][j] = __builtin_amdgcn_mfma_f32_16x16x32_bf16(a[i], b[j], acc[i][j], 0, 0, 0);
    }
    __syncthreads();
  }

#pragma unroll
  for (int i = 0; i < 4; i++) {
#pragma unroll
    for (int j = 0; j < 4; j++) {
      const int n = bn * 128 + wn * 64 + j * 16 + lr;
      const float bsv = bias[n];
      const int h = n >> 6, d = n & 63;
#pragma unroll
      for (int r = 0; r < 4; r++) {
        const int m = bm * 128 + wm * 64 + i * 16 + quad * 4 + r;
        const int t = m >> 1, bb = m & 1;
        float v = acc[i][j][r] + bsv;
        dst[((size_t)(bb * NH + h) * T_SEQ + t) * HD + d] = f2bf(v);
      }
    }
  }
}

// ---------------- output projection GEMM ----------------
// out[m][n] = (sum_k Ob[m][k] * Wo[n][k] + bo[n]) * td[m], f32 out
__global__ __launch_bounds__(256, 2) void gemm_out(
    const u16* __restrict__ Ob, const u16* __restrict__ wo,
    const float* __restrict__ bo, const float* __restrict__ td,
    float* __restrict__ out) {
  __shared__ short As[128 * 72];
  __shared__ short Bs[128 * 72];

  const int tid = threadIdx.x;
  const int bm = blockIdx.x, bn = blockIdx.y;
  const int lane = tid & 63, wv_id = tid >> 6;
  const int wm = wv_id >> 1, wn = wv_id & 1;
  const int lr = lane & 15, quad = lane >> 4;

  fx4_t acc[4][4];
#pragma unroll
  for (int i = 0; i < 4; i++)
#pragma unroll
    for (int j = 0; j < 4; j++) acc[i][j] = (fx4_t){0.f, 0.f, 0.f, 0.f};

  for (int k0 = 0; k0 < EMB; k0 += 64) {
#pragma unroll
    for (int it = 0; it < 4; ++it) {
      int g = tid + it * 256;
      int r = g >> 3, c = g & 7;
      const int4* sa = (const int4*)(Ob + (size_t)(bm * 128 + r) * EMB + k0 + c * 8);
      *(int4*)&As[r * 72 + c * 8] = *sa;
      const int4* sb = (const int4*)(wo + (size_t)(bn * 128 + r) * EMB + k0 + c * 8);
      *(int4*)&Bs[r * 72 + c * 8] = *sb;
    }
    __syncthreads();
#pragma unroll
    for (int ks = 0; ks < 2; ++ks) {
      bf16x8_t a[4], b[4];
      const int goff = (ks * 4 + quad) * 8;
#pragma unroll
      for (int i = 0; i < 4; i++) a[i] = *(const bf16x8_t*)&As[(wm * 64 + i * 16 + lr) * 72 + goff];
#pragma unroll
      for (int j = 0; j < 4; j++) b[j] = *(const bf16x8_t*)&Bs[(wn * 64 + j * 16 + lr) * 72 + goff];
#pragma unroll
      for (int i = 0; i < 4; i++)
#pragma unroll
        for (int j = 0; j < 4; j++)
          acc[i][j] = __builtin_amdgcn_mfma_f32_16x16x32_bf16(a[i], b[j], acc[i][j], 0, 0, 0);
    }
    __syncthreads();
  }

#pragma unroll
  for (int i = 0; i < 4; i++) {
#pragma unroll
    for (int j = 0; j < 4; j++) {
      const int n = bn * 128 + wn * 64 + j * 16 + lr;
      const float bsv = bo[n];
#pragma unroll
      for (int r = 0; r < 4; r++) {
        const int m = bm * 128 + wm * 64 + i * 16 + quad * 4 + r;
        float v = (acc[i][j][r] + bsv) * td[m];
        out[(size_t)m * EMB + n] = v;
      }
    }
  }
}

// ---------------- flash attention with MFMA ----------------
// Block: 128 Q-rows of one (b,h). 4 waves x 32 Q-rows. K-tiles of 64.
// S = Q K^T via mfma 16x16x32 (A=Q frag, B=K rows from LDS).
// Online softmax on C-layout (col=lane&15, row=quad*4+reg).
// P -> per-wave LDS (C-layout scatter writes) -> A-layout b128 reads.
// V staged transposed (Vt[d][k]) for B-operand b128 reads.
__global__ __launch_bounds__(256, 2) void attn_mfma(
    const u16* __restrict__ Qh, const u16* __restrict__ Kh, const u16* __restrict__ Vh,
    u16* __restrict__ Ob) {
  __shared__ short Ks[64 * 72];      // K-tile, row-major [k][d]
  __shared__ short Vt[64 * 72];      // V-tile transposed [d][k]
  __shared__ short Ps[4][32 * 72];   // per-wave P buffer [q_local][k_local]

  const int blk = blockIdx.x;
  const int bh = blk & 31;
  const int j = blk >> 5;                    // 0..15
  const int qt = (j < 8) ? (15 - j) : (j - 8); // pair (i, i+256) sums to 15 -> CU balance
  const int qb = qt * 128;

  const int tid = threadIdx.x;
  const int w = tid >> 6, lane = tid & 63;
  const int lr = lane & 15, quad = lane >> 4;

  const u16* Qb = Qh + (size_t)bh * T_SEQ * HD;
  const u16* Kb = Kh + (size_t)bh * T_SEQ * HD;
  const u16* Vb = Vh + (size_t)bh * T_SEQ * HD;

  // Q fragments, pre-scaled by 1/sqrt(64)=0.125 (exact in bf16: exponent shift)
  bf16x8_t qf[2][2];
#pragma unroll
  for (int mt = 0; mt < 2; mt++)
#pragma unroll
    for (int ks = 0; ks < 2; ks++) {
      bf16x8_t v = *(const bf16x8_t*)(Qb + (size_t)(qb + w * 32 + mt * 16 + lr) * HD + ks * 32 + quad * 8);
      bf16x8_t o;
#pragma unroll
      for (int e = 0; e < 8; e++) o[e] = (short)f2bf(bf2f((u16)v[e]) * 0.125f);
      qf[mt][ks] = o;
    }

  fx4_t acc_o[2][4];
  float m_i[2][4], l_i[2][4];
#pragma unroll
  for (int mt = 0; mt < 2; mt++)
#pragma unroll
    for (int r = 0; r < 4; r++) { m_i[mt][r] = -1e30f; l_i[mt][r] = 0.f; }
#pragma unroll
  for (int mt = 0; mt < 2; mt++)
#pragma unroll
    for (int dn = 0; dn < 4; dn++) acc_o[mt][dn] = (fx4_t){0.f, 0.f, 0.f, 0.f};

  const int nkt = qb / 64 + 2; // causal: K-tiles cover [0, qb+128)
  for (int kt = 0; kt < nkt; kt++) {
    const int k0 = kt * 64;
    __syncthreads(); // protect Ks/Vt from previous iteration's readers

    // stage K (row-major) and V (transposed, rotated-issue scatter: conflict-free)
#pragma unroll
    for (int it = 0; it < 2; it++) {
      int g = tid + it * 256;       // 0..511: 64 rows x 8 chunks of 8 bf16
      int r = g >> 3, c8 = (g & 7) * 8;
      *(int4*)&Ks[r * 72 + c8] = *(const int4*)(Kb + (size_t)(k0 + r) * HD + c8);
      int4 vv = *(const int4*)(Vb + (size_t)(k0 + r) * HD + c8);
      const u16* vs = (const u16*)&vv;
#pragma unroll
      for (int e = 0; e < 8; e++) {
        int ee = (e + lane) & 7;     // issue-order rotation only; layout unchanged
        Vt[(c8 + ee) * 72 + r] = vs[ee];
      }
    }
    __syncthreads();

    // S = Q K^T (scale folded into Q)
    fx4_t s[2][4];
#pragma unroll
    for (int mt = 0; mt < 2; mt++)
#pragma unroll
      for (int nt = 0; nt < 4; nt++) s[mt][nt] = (fx4_t){0.f, 0.f, 0.f, 0.f};
#pragma unroll
    for (int ks = 0; ks < 2; ks++) {
      bf16x8_t kf[4];
#pragma unroll
      for (int nt = 0; nt < 4; nt++)
        kf[nt] = *(const bf16x8_t*)&Ks[(nt * 16 + lr) * 72 + ks * 32 + quad * 8];
#pragma unroll
      for (int mt = 0; mt < 2; mt++)
#pragma unroll
        for (int nt = 0; nt < 4; nt++)
          s[mt][nt] = __builtin_amdgcn_mfma_f32_16x16x32_bf16(qf[mt][ks], kf[nt], s[mt][nt], 0, 0, 0);
    }

    // causal mask (only near-diagonal tiles do work)
    if (k0 + 63 > qb + w * 32) {
#pragma unroll
      for (int mt = 0; mt < 2; mt++)
#pragma unroll
        for (int nt = 0; nt < 4; nt++)
#pragma unroll
          for (int r = 0; r < 4; r++) {
            const int q = qb + w * 32 + mt * 16 + quad * 4 + r;
            const int k = k0 + nt * 16 + lr;
            if (k > q) s[mt][nt][r] = -1e30f;
          }
    }

    // online softmax per q-row (rows live in quad groups: reduce over 16 lanes)
#pragma unroll
    for (int mt = 0; mt < 2; mt++) {
#pragma unroll
      for (int r = 0; r < 4; r++) {
        float rmax = fmaxf(fmaxf(s[mt][0][r], s[mt][1][r]), fmaxf(s[mt][2][r], s[mt][3][r]));
        rmax = fmaxf(rmax, __shfl_xor(rmax, 1));
        rmax = fmaxf(rmax, __shfl_xor(rmax, 2));
        rmax = fmaxf(rmax, __shfl_xor(rmax, 4));
        rmax = fmaxf(rmax, __shfl_xor(rmax, 8));
        const float mo = m_i[mt][r];
        const float mn = fmaxf(mo, rmax);
        const float alpha = __expf(mo - mn);
        float rsum = 0.f;
#pragma unroll
        for (int nt = 0; nt < 4; nt++) {
          float e = __expf(s[mt][nt][r] - mn);
          s[mt][nt][r] = e;
          rsum += e;
        }
        rsum += __shfl_xor(rsum, 1);
        rsum += __shfl_xor(rsum, 2);
        rsum += __shfl_xor(rsum, 4);
        rsum += __shfl_xor(rsum, 8);
        l_i[mt][r] = l_i[mt][r] * alpha + rsum;
        m_i[mt][r] = mn;
#pragma unroll
        for (int dn = 0; dn < 4; dn++) acc_o[mt][dn][r] *= alpha;
      }
    }

    // P (C-layout) -> per-wave LDS -> A-layout fragments
    short* Pw = Ps[w];
#pragma unroll
    for (int mt = 0; mt < 2; mt++)
#pragma unroll
      for (int nt = 0; nt < 4; nt++)
#pragma unroll
        for (int r = 0; r < 4; r++)
          Pw[(mt * 16 + quad * 4 + r) * 72 + nt * 16 + lr] = (short)f2bf(s[mt][nt][r]);
    // wave-synchronous: compiler inserts lgkmcnt wait before dependent reads

    // O += P V
#pragma unroll
    for (int ks = 0; ks < 2; ks++) {
      bf16x8_t pf[2], vf[4];
#pragma unroll
      for (int mt = 0; mt < 2; mt++)
        pf[mt] = *(const bf16x8_t*)&Pw[(mt * 16 + lr) * 72 + ks * 32 + quad * 8];
#pragma unroll
      for (int dn = 0; dn < 4; dn++)
        vf[dn] = *(const bf16x8_t*)&Vt[(dn * 16 + lr) * 72 + ks * 32 + quad * 8];
#pragma unroll
      for (int mt = 0; mt < 2; mt++)
#pragma unroll
        for (int dn = 0; dn < 4; dn++)
          acc_o[mt][dn] = __builtin_amdgcn_mfma_f32_16x16x32_bf16(pf[mt], vf[dn], acc_o[mt][dn], 0, 0, 0);
    }
  }

  // epilogue: normalize, write Ob[(t*B+b)*E + h*64 + d]
  const int b = bh >> 4, h = bh & 15;
#pragma unroll
  for (int mt = 0; mt < 2; mt++) {
    float inv[4];
#pragma unroll
    for (int r = 0; r < 4; r++) inv[r] = 1.0f / l_i[mt][r];
#pragma unroll
    for (int dn = 0; dn < 4; dn++) {
#pragma unroll
      for (int r = 0; r < 4; r++) {
        const int t = qb + w * 32 + mt * 16 + quad * 4 + r;
        const int d = dn * 16 + lr;
        Ob[(size_t)(t * BATCH + b) * EMB + h * HD + d] = f2bf(acc_o[mt][dn][r] * inv[r]);
      }
    }
  }
}

// ---------------- launch ----------------
extern "C" void kernel_launch(void* const* d_in, const int* in_sizes, int n_in,
                              void* d_out, int out_size, void* d_ws, size_t ws_size,
                              hipStream_t stream) {
  const float* x  = (const float*)d_in[0];
  const float* td = (const float*)d_in[1];
  // d_in[2] attn_mask: fixed causal tril, handled analytically
  const float* Wq = (const float*)d_in[3];
  const float* bq = (const float*)d_in[4];
  const float* Wk = (const float*)d_in[5];
  const float* bk = (const float*)d_in[6];
  const float* Wv = (const float*)d_in[7];
  const float* bv = (const float*)d_in[8];
  const float* Wo = (const float*)d_in[9];
  const float* bo = (const float*)d_in[10];
  float* out = (float*)d_out;

  char* ws = (char*)d_ws;
  u16* xb  = (u16*)(ws + 0);                     // 8 MB (reused as Ob after gemm_qkv)
  u16* wqb = (u16*)(ws + ((size_t)8  << 20));    // 2 MB
  u16* wkb = (u16*)(ws + ((size_t)10 << 20));    // 2 MB
  u16* wvb = (u16*)(ws + ((size_t)12 << 20));    // 2 MB
  u16* wob = (u16*)(ws + ((size_t)14 << 20));    // 2 MB
  u16* Qh  = (u16*)(ws + ((size_t)16 << 20));    // 8 MB
  u16* Kh  = (u16*)(ws + ((size_t)24 << 20));    // 8 MB
  u16* Vh  = (u16*)(ws + ((size_t)32 << 20));    // 8 MB  (total 40 MB)
  u16* Ob  = xb;                                  // alias: xb dead after gemm_qkv

  cvt_f32_bf16<<<(MROWS * EMB / 4 + 255) / 256, 256, 0, stream>>>(x, xb, MROWS * EMB / 4);
  cvt_f32_bf16<<<(EMB * EMB / 4 + 255) / 256, 256, 0, stream>>>(Wq, wqb, EMB * EMB / 4);
  cvt_f32_bf16<<<(EMB * EMB / 4 + 255) / 256, 256, 0, stream>>>(Wk, wkb, EMB * EMB / 4);
  cvt_f32_bf16<<<(EMB * EMB / 4 + 255) / 256, 256, 0, stream>>>(Wv, wvb, EMB * EMB / 4);
  cvt_f32_bf16<<<(EMB * EMB / 4 + 255) / 256, 256, 0, stream>>>(Wo, wob, EMB * EMB / 4);

  gemm_qkv<<<dim3(MROWS / 128, EMB / 128, 3), 256, 0, stream>>>(
      xb, wqb, wkb, wvb, bq, bk, bv, Qh, Kh, Vh);

  attn_mfma<<<512, 256, 0, stream>>>(Qh, Kh, Vh, Ob);

  gemm_out<<<dim3(MROWS / 128, EMB / 128), 256, 0, stream>>>(Ob, wob, bo, td, out);
}

// Round 4
// 222.840 us; speedup vs baseline: 7.5615x; 1.2805x over previous
//
#include <hip/hip_runtime.h>

// TimeDecayMultiheadAttention on MI355X (gfx950)
// T=2048, B=2, E=1024, H=16, D=64. All math in bf16 MFMA / fp32 accum.
//
// Pipeline:
//  1) cvt_all: x + 4 weights f32 -> bf16 (one launch)
//  2) gemm_qkv: C = xb @ W^T + b; Q,K scattered to (B,H,T,D); V to (B,H,D,T) [transposed]
//  3) attn_mfma2: flash causal attention, S^T trick, MFMA QK^T + PV -> Ob bf16
//  4) gemm_out: out = (Ob @ Wo^T + bo) * time_decay -> f32 d_out

typedef unsigned short u16;
typedef __attribute__((ext_vector_type(8))) short bf16x8_t;  // 8 bf16 (4 VGPRs)
typedef __attribute__((ext_vector_type(4))) float fx4_t;     // 4 fp32 acc

#define T_SEQ 2048
#define BATCH 2
#define EMB   1024
#define NH    16
#define HD    64
#define MROWS (T_SEQ * BATCH) // 4096

#define EXP2F(x) __builtin_amdgcn_exp2f(x)   // v_exp_f32 (2^x); __exp2f collides with glibc

__device__ __forceinline__ float bf2f(u16 u) {
  union { unsigned int i; float f; } v;
  v.i = ((unsigned int)u) << 16;
  return v.f;
}
__device__ __forceinline__ u16 f2bf(float f) {
  union { float f; unsigned int i; } v;
  v.f = f;
  unsigned int x = v.i;
  unsigned int r = (x + 0x7fffu + ((x >> 16) & 1u)) >> 16; // round-nearest-even
  return (u16)r;
}

// ---------------- conversion: f32 -> bf16, all 5 tensors in one launch ----------------
// granules of 4 f32: x 1048576, then 262144 per weight
__global__ void cvt_all(const float* __restrict__ x,
                        const float* __restrict__ wq, const float* __restrict__ wk,
                        const float* __restrict__ wv, const float* __restrict__ wo,
                        u16* __restrict__ xb,
                        u16* __restrict__ wqb, u16* __restrict__ wkb,
                        u16* __restrict__ wvb, u16* __restrict__ wob) {
  int i = blockIdx.x * blockDim.x + threadIdx.x;
  const float* src; u16* dst; int off;
  if (i < 1048576)      { src = x;  dst = xb;  off = i; }
  else if (i < 1310720) { src = wq; dst = wqb; off = i - 1048576; }
  else if (i < 1572864) { src = wk; dst = wkb; off = i - 1310720; }
  else if (i < 1835008) { src = wv; dst = wvb; off = i - 1572864; }
  else                  { src = wo; dst = wob; off = i - 1835008; }
  float4 v = ((const float4*)src)[off];
  ushort4 o;
  o.x = f2bf(v.x); o.y = f2bf(v.y); o.z = f2bf(v.z); o.w = f2bf(v.w);
  ((ushort4*)dst)[off] = o;
}

// ---------------- QKV projection GEMM ----------------
// C[m][n] = sum_k xb[m][k] * W[n][k] + bias[n]  (m in 4096, n in 1024, k in 1024)
// Q,K: dst[((b*16+h)*2048+t)*64+d]; V: transposed dst[((b*16+h)*64+d)*2048+t]
__global__ __launch_bounds__(256, 2) void gemm_qkv(
    const u16* __restrict__ xb,
    const u16* __restrict__ wq, const u16* __restrict__ wk, const u16* __restrict__ wv,
    const float* __restrict__ bq, const float* __restrict__ bk, const float* __restrict__ bv,
    u16* __restrict__ Qh, u16* __restrict__ Kh, u16* __restrict__ VTg) {
  __shared__ short As[128 * 72]; // 72-elem row stride
  __shared__ short Bs[128 * 72];

  const int z = blockIdx.z;
  const u16* W = (z == 0) ? wq : (z == 1) ? wk : wv;
  const float* bias = (z == 0) ? bq : (z == 1) ? bk : bv;
  u16* dst = (z == 0) ? Qh : (z == 1) ? Kh : VTg;

  const int tid = threadIdx.x;
  const int bm = blockIdx.x, bn = blockIdx.y;
  const int lane = tid & 63, wv_id = tid >> 6;
  const int wm = wv_id >> 1, wn = wv_id & 1;
  const int lr = lane & 15, quad = lane >> 4;

  fx4_t acc[4][4];
#pragma unroll
  for (int i = 0; i < 4; i++)
#pragma unroll
    for (int j = 0; j < 4; j++) acc[i][j] = (fx4_t){0.f, 0.f, 0.f, 0.f};

  for (int k0 = 0; k0 < EMB; k0 += 64) {
#pragma unroll
    for (int it = 0; it < 4; ++it) {
      int g = tid + it * 256;        // 1024 granules of 8 bf16
      int r = g >> 3, c = g & 7;
      const int4* sa = (const int4*)(xb + (size_t)(bm * 128 + r) * EMB + k0 + c * 8);
      *(int4*)&As[r * 72 + c * 8] = *sa;
      const int4* sb = (const int4*)(W + (size_t)(bn * 128 + r) * EMB + k0 + c * 8);
      *(int4*)&Bs[r * 72 + c * 8] = *sb;
    }
    __syncthreads();
#pragma unroll
    for (int ks = 0; ks < 2; ++ks) {
      bf16x8_t a[4], b[4];
      const int goff = (ks * 4 + quad) * 8;
#pragma unroll
      for (int i = 0; i < 4; i++) a[i] = *(const bf16x8_t*)&As[(wm * 64 + i * 16 + lr) * 72 + goff];
#pragma unroll
      for (int j = 0; j < 4; j++) b[j] = *(const bf16x8_t*)&Bs[(wn * 64 + j * 16 + lr) * 72 + goff];
#pragma unroll
      for (int i = 0; i < 4; i++)
#pragma unroll
        for (int j = 0; j < 4; j++)
          acc[i][j] = __builtin_amdgcn_mfma_f32_16x16x32_bf16(a[i], b[j], acc[i][j], 0, 0, 0);
    }
    __syncthreads();
  }

#pragma unroll
  for (int i = 0; i < 4; i++) {
#pragma unroll
    for (int j = 0; j < 4; j++) {
      const int n = bn * 128 + wn * 64 + j * 16 + lr;
      const float bsv = bias[n];
      const int h = n >> 6, d = n & 63;
#pragma unroll
      for (int r = 0; r < 4; r++) {
        const int m = bm * 128 + wm * 64 + i * 16 + quad * 4 + r;
        const int t = m >> 1, bb = m & 1;
        float v = acc[i][j][r] + bsv;
        if (z == 2) {
          // V transposed: VT[(b*16+h)*64 + d][t]   (L2 merges: block covers full t-lines)
          dst[((size_t)(bb * NH + h) * HD + d) * T_SEQ + t] = f2bf(v);
        } else {
          dst[((size_t)(bb * NH + h) * T_SEQ + t) * HD + d] = f2bf(v);
        }
      }
    }
  }
}

// ---------------- output projection GEMM ----------------
// out[m][n] = (sum_k Ob[m][k] * Wo[n][k] + bo[n]) * td[m], f32 out
__global__ __launch_bounds__(256, 2) void gemm_out(
    const u16* __restrict__ Ob, const u16* __restrict__ wo,
    const float* __restrict__ bo, const float* __restrict__ td,
    float* __restrict__ out) {
  __shared__ short As[128 * 72];
  __shared__ short Bs[128 * 72];

  const int tid = threadIdx.x;
  const int bm = blockIdx.x, bn = blockIdx.y;
  const int lane = tid & 63, wv_id = tid >> 6;
  const int wm = wv_id >> 1, wn = wv_id & 1;
  const int lr = lane & 15, quad = lane >> 4;

  fx4_t acc[4][4];
#pragma unroll
  for (int i = 0; i < 4; i++)
#pragma unroll
    for (int j = 0; j < 4; j++) acc[i][j] = (fx4_t){0.f, 0.f, 0.f, 0.f};

  for (int k0 = 0; k0 < EMB; k0 += 64) {
#pragma unroll
    for (int it = 0; it < 4; ++it) {
      int g = tid + it * 256;
      int r = g >> 3, c = g & 7;
      const int4* sa = (const int4*)(Ob + (size_t)(bm * 128 + r) * EMB + k0 + c * 8);
      *(int4*)&As[r * 72 + c * 8] = *sa;
      const int4* sb = (const int4*)(wo + (size_t)(bn * 128 + r) * EMB + k0 + c * 8);
      *(int4*)&Bs[r * 72 + c * 8] = *sb;
    }
    __syncthreads();
#pragma unroll
    for (int ks = 0; ks < 2; ++ks) {
      bf16x8_t a[4], b[4];
      const int goff = (ks * 4 + quad) * 8;
#pragma unroll
      for (int i = 0; i < 4; i++) a[i] = *(const bf16x8_t*)&As[(wm * 64 + i * 16 + lr) * 72 + goff];
#pragma unroll
      for (int j = 0; j < 4; j++) b[j] = *(const bf16x8_t*)&Bs[(wn * 64 + j * 16 + lr) * 72 + goff];
#pragma unroll
      for (int i = 0; i < 4; i++)
#pragma unroll
        for (int j = 0; j < 4; j++)
          acc[i][j] = __builtin_amdgcn_mfma_f32_16x16x32_bf16(a[i], b[j], acc[i][j], 0, 0, 0);
    }
    __syncthreads();
  }

#pragma unroll
  for (int i = 0; i < 4; i++) {
#pragma unroll
    for (int j = 0; j < 4; j++) {
      const int n = bn * 128 + wn * 64 + j * 16 + lr;
      const float bsv = bo[n];
#pragma unroll
      for (int r = 0; r < 4; r++) {
        const int m = bm * 128 + wm * 64 + i * 16 + quad * 4 + r;
        float v = (acc[i][j][r] + bsv) * td[m];
        out[(size_t)m * EMB + n] = v;
      }
    }
  }
}

// ---------------- flash attention v2: S^T trick, Q-tile 64, 1024 blocks ----------------
// Block: 64 Q-rows of one (b,h); wave w owns q in [qb+w*16, +16). K-tiles of 64.
// S^T = K Q^T  (A = K rows from LDS, B = Q frags). C-layout: lane holds
// S[q=lr][k = nt*16 + quad*4 + r]  -> softmax reduce = 2 shfl_xor (16,32),
// P^T store = b64 writes (4 contiguous k), P read back = b128 A-frags.
// V^T staged from global VT (no transpose scatter). exp2-domain softmax.
__global__ __launch_bounds__(256, 4) void attn_mfma2(
    const u16* __restrict__ Qh, const u16* __restrict__ Kh, const u16* __restrict__ VTg,
    u16* __restrict__ Ob) {
  __shared__ short Ks[64 * 72];     // K-tile row-major [k_local][d]
  __shared__ short Vt[64 * 72];     // V^T tile [d][k_local]
  __shared__ short Ps[4][16 * 72];  // per-wave P [q_local][k_local]

  const int blk = blockIdx.x;
  const int bh = blk & 31;
  const int j = blk >> 5;                       // 0..31
  const int qt = (j & 1) ? (31 - (j >> 1)) : (j >> 1); // consecutive pairs sum to 31
  const int qb = qt * 64;

  const int tid = threadIdx.x;
  const int w = tid >> 6, lane = tid & 63;
  const int lr = lane & 15, quad = lane >> 4;

  const u16* Qb = Qh + (size_t)bh * T_SEQ * HD;
  const u16* Kb = Kh + (size_t)bh * T_SEQ * HD;
  const u16* VTb = VTg + (size_t)bh * HD * T_SEQ;

  // Q fragment as MFMA B-operand: lane holds Q[q=qb+w*16+lr][d=ks*32+quad*8+jj]
  // scale = 1/sqrt(64) * log2(e)  (exp2-domain softmax)
  const float QSCALE = 0.18033688f;
  bf16x8_t qf[2];
#pragma unroll
  for (int ks = 0; ks < 2; ks++) {
    bf16x8_t v = *(const bf16x8_t*)(Qb + (size_t)(qb + w * 16 + lr) * HD + ks * 32 + quad * 8);
    bf16x8_t o;
#pragma unroll
    for (int e = 0; e < 8; e++) o[e] = (short)f2bf(bf2f((u16)v[e]) * QSCALE);
    qf[ks] = o;
  }

  fx4_t acc_o[4];                    // O C-layout: row q_local=quad*4+r, col d=dn*16+lr
#pragma unroll
  for (int dn = 0; dn < 4; dn++) acc_o[dn] = (fx4_t){0.f, 0.f, 0.f, 0.f};
  float m_i = -1e30f, l_i = 0.f;     // stats for q = qb + w*16 + lr (replicated over quads)

  const int nkt = qt + 1;
  for (int kt = 0; kt < nkt; kt++) {
    const int k0 = kt * 64;
    __syncthreads(); // protect Ks/Vt from previous iteration's readers

    // stage K (row-major) and V^T (row-major in [d][k]) — pure int4 copies
#pragma unroll
    for (int it = 0; it < 2; it++) {
      int g = tid + it * 256;       // 512 chunks: 64 rows x 8 chunks of 8 bf16
      int r = g >> 3, c8 = (g & 7) * 8;
      *(int4*)&Ks[r * 72 + c8] = *(const int4*)(Kb + (size_t)(k0 + r) * HD + c8);
      *(int4*)&Vt[r * 72 + c8] = *(const int4*)(VTb + (size_t)r * T_SEQ + k0 + c8);
    }
    __syncthreads();

    // S^T = K Q^T : st[nt] C-layout row = k_local = nt*16+quad*4+r, col = q_local = lr
    fx4_t st[4];
#pragma unroll
    for (int nt = 0; nt < 4; nt++) st[nt] = (fx4_t){0.f, 0.f, 0.f, 0.f};
#pragma unroll
    for (int ks = 0; ks < 2; ks++) {
#pragma unroll
      for (int nt = 0; nt < 4; nt++) {
        bf16x8_t kf = *(const bf16x8_t*)&Ks[(nt * 16 + lr) * 72 + ks * 32 + quad * 8];
        st[nt] = __builtin_amdgcn_mfma_f32_16x16x32_bf16(kf, qf[ks], st[nt], 0, 0, 0);
      }
    }

    // causal mask: only the diagonal tile needs it (k0 == qb covers all waves' q)
    if (kt == qt) {
#pragma unroll
      for (int nt = 0; nt < 4; nt++)
#pragma unroll
        for (int r = 0; r < 4; r++)
          if (nt * 16 + quad * 4 + r > w * 16 + lr) st[nt][r] = -1e30f;
    }

    // online softmax (exp2 domain); row = q = lr, reduce across quads only
    float rmax = -1e30f;
#pragma unroll
    for (int nt = 0; nt < 4; nt++)
#pragma unroll
      for (int r = 0; r < 4; r++) rmax = fmaxf(rmax, st[nt][r]);
    rmax = fmaxf(rmax, __shfl_xor(rmax, 16));
    rmax = fmaxf(rmax, __shfl_xor(rmax, 32));
    const float mn = fmaxf(m_i, rmax);
    const float alpha = EXP2F(m_i - mn);
    m_i = mn;
    float rsum = 0.f;
#pragma unroll
    for (int nt = 0; nt < 4; nt++) {
#pragma unroll
      for (int r = 0; r < 4; r++) {
        float e = EXP2F(st[nt][r] - mn);
        st[nt][r] = e;
        rsum += e;
      }
    }
    rsum += __shfl_xor(rsum, 16);
    rsum += __shfl_xor(rsum, 32);
    l_i = l_i * alpha + rsum;

    // P store: row q_local = lr, cols k = nt*16 + quad*4 + [0..3] -> b64 writes
    short* Pw = Ps[w];
#pragma unroll
    for (int nt = 0; nt < 4; nt++) {
      short4 pv;
      pv.x = (short)f2bf(st[nt][0]);
      pv.y = (short)f2bf(st[nt][1]);
      pv.z = (short)f2bf(st[nt][2]);
      pv.w = (short)f2bf(st[nt][3]);
      *(short4*)&Pw[lr * 72 + nt * 16 + quad * 4] = pv;
    }

    // rescale O by alpha broadcast into C-layout rows (q_local = quad*4+r)
#pragma unroll
    for (int r = 0; r < 4; r++) {
      const float a_r = __shfl(alpha, quad * 4 + r);
#pragma unroll
      for (int dn = 0; dn < 4; dn++) acc_o[dn][r] *= a_r;
    }

    // O += P V : pf = A-frag from Ps row lr; vf = B-frag from Vt[d][k]
#pragma unroll
    for (int ks = 0; ks < 2; ks++) {
      bf16x8_t pf = *(const bf16x8_t*)&Pw[lr * 72 + ks * 32 + quad * 8];
#pragma unroll
      for (int dn = 0; dn < 4; dn++) {
        bf16x8_t vf = *(const bf16x8_t*)&Vt[(dn * 16 + lr) * 72 + ks * 32 + quad * 8];
        acc_o[dn] = __builtin_amdgcn_mfma_f32_16x16x32_bf16(pf, vf, acc_o[dn], 0, 0, 0);
      }
    }
  }

  // epilogue: normalize (1/l broadcast into C-layout), write Ob[(t*B+b)*E + h*64 + d]
  const float inv = 1.0f / l_i;
  const int b = bh >> 4, h = bh & 15;
#pragma unroll
  for (int r = 0; r < 4; r++) {
    const float inv_r = __shfl(inv, quad * 4 + r);
    const int t = qb + w * 16 + quad * 4 + r;
#pragma unroll
    for (int dn = 0; dn < 4; dn++) {
      const int d = dn * 16 + lr;
      Ob[(size_t)(t * BATCH + b) * EMB + h * HD + d] = f2bf(acc_o[dn][r] * inv_r);
    }
  }
}

// ---------------- launch ----------------
extern "C" void kernel_launch(void* const* d_in, const int* in_sizes, int n_in,
                              void* d_out, int out_size, void* d_ws, size_t ws_size,
                              hipStream_t stream) {
  const float* x  = (const float*)d_in[0];
  const float* td = (const float*)d_in[1];
  // d_in[2] attn_mask: fixed causal tril, handled analytically
  const float* Wq = (const float*)d_in[3];
  const float* bq = (const float*)d_in[4];
  const float* Wk = (const float*)d_in[5];
  const float* bk = (const float*)d_in[6];
  const float* Wv = (const float*)d_in[7];
  const float* bv = (const float*)d_in[8];
  const float* Wo = (const float*)d_in[9];
  const float* bo = (const float*)d_in[10];
  float* out = (float*)d_out;

  char* ws = (char*)d_ws;
  u16* xb  = (u16*)(ws + 0);                     // 8 MB (reused as Ob after gemm_qkv)
  u16* wqb = (u16*)(ws + ((size_t)8  << 20));    // 2 MB
  u16* wkb = (u16*)(ws + ((size_t)10 << 20));    // 2 MB
  u16* wvb = (u16*)(ws + ((size_t)12 << 20));    // 2 MB
  u16* wob = (u16*)(ws + ((size_t)14 << 20));    // 2 MB
  u16* Qh  = (u16*)(ws + ((size_t)16 << 20));    // 8 MB
  u16* Kh  = (u16*)(ws + ((size_t)24 << 20));    // 8 MB
  u16* VTg = (u16*)(ws + ((size_t)32 << 20));    // 8 MB  (V stored transposed; total 40 MB)
  u16* Ob  = xb;                                  // alias: xb dead after gemm_qkv

  cvt_all<<<8192, 256, 0, stream>>>(x, Wq, Wk, Wv, Wo, xb, wqb, wkb, wvb, wob);

  gemm_qkv<<<dim3(MROWS / 128, EMB / 128, 3), 256, 0, stream>>>(
      xb, wqb, wkb, wvb, bq, bk, bv, Qh, Kh, VTg);

  attn_mfma2<<<1024, 256, 0, stream>>>(Qh, Kh, VTg, Ob);

  gemm_out<<<dim3(MROWS / 128, EMB / 128), 256, 0, stream>>>(Ob, wob, bo, td, out);
}